// Round 16
// baseline (84.709 us; speedup 1.0000x reference)
//
#include <hip/hip_runtime.h>
#include <cstdint>

#define CD 64
#define HWD 589824
#define K1_BLOCKS 1152
#define TPB 4                        // 128-col tiles per block (512-col span)
#define K1_ROWS (K1_BLOCKS * 4)      // 4608 cell rows (one per wave)
#define RPB (K1_ROWS / 64)           // 72 rows per k2a block
#define FMAXV 3.402823466e+38f

typedef float f32x16 __attribute__((ext_vector_type(16)));
typedef float f32x4v __attribute__((ext_vector_type(4)));
typedef short bf16x8 __attribute__((ext_vector_type(8)));

__device__ __forceinline__ short f2bf(float f) {
    unsigned u = __float_as_uint(f);
    u = u + 0x7FFFu + ((u >> 16) & 1u);   // RNE
    return (short)(u >> 16);
}

// nontemporal float4 load: bypass L2/L3 allocation (streaming path)
__device__ __forceinline__ float4 nt_load4(const float* p) {
    f32x4v v = __builtin_nontemporal_load((const f32x4v*)p);
    return make_float4(v.x, v.y, v.z, v.w);
}

// sorted top-4 insert: t.x <= t.y <= t.z <= t.w
__device__ __forceinline__ void ins4(float4& t, float x) {
    if (x < t.w) {
        if (x < t.z) { t.w = t.z;
            if (x < t.y) { t.z = t.y;
                if (x < t.x) { t.y = t.x; t.x = x; } else t.y = x;
            } else t.z = x;
        } else t.w = x;
    }
}

// kA: 64 blocks x 64 thr; thread k of block p loads one sel element.
__global__ __launch_bounds__(64) void kA_pack(
    const float* __restrict__ f1, const int* __restrict__ nidx,
    short* __restrict__ sel_bf, float* __restrict__ sel2,
    unsigned* __restrict__ ticket)
{
    const int p = blockIdx.x, k = threadIdx.x;
    if (p == 0 && k == 0) *ticket = 0u;
    float v = f1[(long)k * HWD + nidx[p]];
    float s = v * v;
#pragma unroll
    for (int off = 32; off; off >>= 1) s += __shfl_xor(s, off);
    sel_bf[p * CD + k] = f2bf(v);
    if (k == 0) sel2[p] = s;
}

// k1: R14 reg-staged async pipeline + NONTEMPORAL loads (L2/L3 bypass test).
__global__ __launch_bounds__(256) void k1_topk(
    const float* __restrict__ f2, const short* __restrict__ sel_bf,
    const float* __restrict__ sel2, float4* __restrict__ cells)
{
    __shared__ float lds[CD][128];   // 32 KB
    const int tid = threadIdx.x;
    const int lane = tid & 63, wid = tid >> 6;
    const int l31 = lane & 31, lh = lane >> 5;
    const long nb = (long)blockIdx.x * (TPB * 128);

    const int srow = tid >> 5;          // 0..7
    const int scol = (tid & 31) * 4;    // float4 column

    bf16x8 sf0[4], sf1[4];
#pragma unroll
    for (int ks = 0; ks < 4; ++ks) {
        sf0[ks] = *(const bf16x8*)(sel_bf + l31 * CD + 16 * ks + 8 * lh);
        sf1[ks] = *(const bf16x8*)(sel_bf + (l31 + 32) * CD + 16 * ks + 8 * lh);
    }
    const float sel20 = sel2[l31], sel21 = sel2[l31 + 32];

    float4 st[8];
#pragma unroll
    for (int i = 0; i < 8; ++i)
        st[i] = nt_load4(f2 + (long)(8 * i + srow) * HWD + nb + scol);
    __builtin_amdgcn_sched_barrier(0);
#pragma unroll
    for (int i = 0; i < 8; ++i)
        *(float4*)&lds[8 * i + srow][scol] = st[i];

    float4 t = make_float4(FMAXV, FMAXV, FMAXV, FMAXV);
    float4 u = t;

#pragma unroll
    for (int tt = 0; tt < TPB; ++tt) {
        if (tt + 1 < TPB) {
#pragma unroll
            for (int i = 0; i < 8; ++i)
                st[i] = nt_load4(f2 + (long)(8 * i + srow) * HWD
                                 + nb + (long)(tt + 1) * 128 + scol);
            __builtin_amdgcn_sched_barrier(0);
        }
        asm volatile("s_waitcnt lgkmcnt(0)" ::: "memory");
        __builtin_amdgcn_sched_barrier(0);
        __builtin_amdgcn_s_barrier();
        __builtin_amdgcn_sched_barrier(0);

        const int col = wid * 32 + l31;
        float fs = 0.f;
        f32x16 a0, a1;
#pragma unroll
        for (int i = 0; i < 16; ++i) { a0[i] = 0.f; a1[i] = 0.f; }
#pragma unroll
        for (int ks = 0; ks < 4; ++ks) {
            bf16x8 af;
#pragma unroll
            for (int j = 0; j < 8; ++j) {
                float v = lds[16 * ks + 8 * lh + j][col];
                fs += v * v;
                af[j] = f2bf(v);
            }
            a0 = __builtin_amdgcn_mfma_f32_32x32x16_bf16(af, sf0[ks], a0, 0, 0, 0);
            a1 = __builtin_amdgcn_mfma_f32_32x32x16_bf16(af, sf1[ks], a1, 0, 0, 0);
        }
        fs += __shfl_xor(fs, 32);

#pragma unroll
        for (int i = 0; i < 16; ++i) {
            int r = (i & 3) + 8 * (i >> 2) + 4 * lh;
            float fr2 = __shfl(fs, r);
            ins4(t, fmaxf(sel20 + fr2 - 2.f * a0[i], 0.f));   // p = l31
            ins4(u, fmaxf(sel21 + fr2 - 2.f * a1[i], 0.f));   // p = l31+32
        }

        asm volatile("s_waitcnt lgkmcnt(0)" ::: "memory");
        __builtin_amdgcn_sched_barrier(0);
        __builtin_amdgcn_s_barrier();
        __builtin_amdgcn_sched_barrier(0);

        if (tt + 1 < TPB) {
#pragma unroll
            for (int i = 0; i < 8; ++i)
                *(float4*)&lds[8 * i + srow][scol] = st[i];
        }
    }

    {   // merge lh halves (lanes l and l^32 hold the same p)
        float4 o;
        o.x = __shfl_xor(t.x, 32); o.y = __shfl_xor(t.y, 32);
        o.z = __shfl_xor(t.z, 32); o.w = __shfl_xor(t.w, 32);
        ins4(t, o.x); ins4(t, o.y); ins4(t, o.z); ins4(t, o.w);
        o.x = __shfl_xor(u.x, 32); o.y = __shfl_xor(u.y, 32);
        o.z = __shfl_xor(u.z, 32); o.w = __shfl_xor(u.w, 32);
        ins4(u, o.x); ins4(u, o.y); ins4(u, o.z); ins4(u, o.w);
    }
    if (lh == 0) {
        const int gw = blockIdx.x * 4 + wid;
        cells[(long)gw * CD + l31]      = t;   // p = l31
        cells[(long)gw * CD + l31 + 32] = u;   // p = l31+32
    }
}

// k2a: 64 blocks x 1024 thr. Block b covers rows [b*72, b*72+72) of
// cells[row][p]. Flat coalesced reads: thread tid always reads column
// p = tid&63. Per-thread top-4 -> cross-wave LDS merge -> exact per-block
// top-4 per p -> cells2[b][p] (coalesced).
__global__ __launch_bounds__(1024) void k2a_screen(
    const float4* __restrict__ cells, float4* __restrict__ cells2)
{
    const int tid = threadIdx.x;
    const int b = blockIdx.x;
    __shared__ float4 lmm[16][64];   // 16 KB

    const float4* base = cells + (long)b * (RPB * 64);
    float4 t = make_float4(FMAXV, FMAXV, FMAXV, FMAXV);
#pragma unroll
    for (int q = 0; q < 4; ++q) {              // 4*1024 of 4608
        float4 v = base[q * 1024 + tid];
        ins4(t, v.x); ins4(t, v.y); ins4(t, v.z); ins4(t, v.w);
    }
    if (tid < RPB * 64 - 4096) {               // tail 512
        float4 v = base[4096 + tid];
        ins4(t, v.x); ins4(t, v.y); ins4(t, v.z); ins4(t, v.w);
    }

    lmm[tid >> 6][tid & 63] = t;
    __syncthreads();

    if (tid < 64) {
        float4 m = make_float4(FMAXV, FMAXV, FMAXV, FMAXV);
#pragma unroll
        for (int w = 0; w < 16; ++w) {
            float4 v = lmm[w][tid];
            ins4(m, v.x); ins4(m, v.y); ins4(m, v.z); ins4(m, v.w);
        }
        cells2[b * 64 + tid] = m;
    }
}

// k2b: 64 blocks x 64 thr; block p: lane w holds cells2[w][p] (sorted top-4),
// 16 rounds of wave-min extraction -> partial[p]; ticket -> ordered final sum.
__global__ __launch_bounds__(64) void k2b_sel(
    const float4* __restrict__ cells2, float* __restrict__ partial,
    unsigned* __restrict__ ticket, float* __restrict__ out)
{
    const int p = blockIdx.x;
    const int lane = threadIdx.x;

    float4 t = cells2[lane * 64 + p];   // already sorted ascending

    float sum = 0.f;
    for (int rd = 0; rd < 16; ++rd) {
        unsigned long long key =
            ((unsigned long long)__float_as_uint(t.x) << 32) | (unsigned)lane;
#pragma unroll
        for (int off = 32; off; off >>= 1) {
            unsigned long long o = __shfl_xor(key, off);
            if (o < key) key = o;
        }
        sum += __uint_as_float((unsigned)(key >> 32));
        if ((unsigned)(key & 0xFFFFFFFFu) == (unsigned)lane) {
            t.x = t.y; t.y = t.z; t.z = t.w; t.w = FMAXV;   // pop local min
        }
    }

    if (lane == 0) {
        partial[p] = sum;
        __threadfence();
        unsigned tk = atomicAdd(ticket, 1u);
        if (tk == CD - 1) {          // last block: deterministic ordered sum
            __threadfence();
            float s = 0.f;
            const volatile float* vp = partial;
            for (int q = 0; q < CD; ++q) s += vp[q];
            out[0] = -s / 1024.0f;
        }
    }
}

extern "C" void kernel_launch(void* const* d_in, const int* in_sizes, int n_in,
                              void* d_out, int out_size, void* d_ws, size_t ws_size,
                              hipStream_t stream)
{
    const float* f1   = (const float*)d_in[0];
    const float* f2   = (const float*)d_in[1];
    const int*   nidx = (const int*)d_in[3];     // negative_indices
    float* out = (float*)d_out;

    float4*   cells   = (float4*)d_ws;                          // 4608*64*16 = 4.7 MB
    float4*   cells2  = cells + (long)K1_ROWS * CD;             // 64*64*16 = 64 KB
    short*    sel_bf  = (short*)(cells2 + 64 * 64);             // 8 KB
    float*    sel2    = (float*)(sel_bf + CD * CD);
    float*    partial = sel2 + CD;
    unsigned* ticket  = (unsigned*)(partial + CD);

    kA_pack   <<<CD,         64, 0, stream>>>(f1, nidx, sel_bf, sel2, ticket);
    k1_topk   <<<K1_BLOCKS, 256, 0, stream>>>(f2, sel_bf, sel2, cells);
    k2a_screen<<<CD,       1024, 0, stream>>>(cells, cells2);
    k2b_sel   <<<CD,         64, 0, stream>>>(cells2, partial, ticket, out);
}